// Round 9
// baseline (63.865 us; speedup 1.0000x reference)
//
#include <hip/hip_runtime.h>
#include <hip/hip_bf16.h>

#define N_POINTS 16384
#define N_GAUSS  3200
#define N_CLASSES 14
#define P2_STRIDE 10            // floats per gaussian coeff record
#define N_SPLITS 25             // 25 splits x 128 gaussians = 3200
#define G_PER_SPLIT 128         // 4 MFMA chunks of 32
#define N_SG (N_POINTS / 512)   // 32 point-supergroups (512 pts per block)

typedef _Float16 half8  __attribute__((ext_vector_type(8)));   // 4 VGPRs
typedef _Float16 half2v __attribute__((ext_vector_type(2)));
typedef float    f32x4  __attribute__((ext_vector_type(4)));

// d_ws layout (total exactly 307,200 B -- proven safe):
//   [0, 128000)         p2:   [3200][10] f32
//   [128000, 217600)    semH: [14][3200] f16   (hi part of semantics)
//   [217600, 307200)    semL: [14][3200] f16   (residual part)
#define WS_P2_OFF   0
#define WS_SEMH_OFF 128000
#define WS_SEML_OFF 217600

// ---------------------------------------------------------------------------
// Prep: per-gaussian quadratic-form coefficients in "P-form":
//   arg = Sum_{k=0..8} P[k]*C[k] + C9,   P = [x^2,y^2,z^2,xy,xz,yz,x,y,z]
//   exp2(arg) = opacity * exp(-0.5*q).
// Semantics transposed to f16 hi+lo pairs: sem = semH + semL (to ~2^-22 rel).
// ---------------------------------------------------------------------------
__global__ void gauss_prep_kernel(const float* __restrict__ means,
                                  const float* __restrict__ scales,
                                  const float* __restrict__ rotations,
                                  const float* __restrict__ opacities,
                                  const float* __restrict__ semantics,
                                  float* __restrict__ p2,
                                  _Float16* __restrict__ semH,
                                  _Float16* __restrict__ semL) {
    int g = blockIdx.x * blockDim.x + threadIdx.x;
    if (g >= N_GAUSS) return;

    float qw = rotations[g * 4 + 0];
    float qx = rotations[g * 4 + 1];
    float qy = rotations[g * 4 + 2];
    float qz = rotations[g * 4 + 3];
    float inv = 1.0f / sqrtf(qw * qw + qx * qx + qy * qy + qz * qz);
    qw *= inv; qx *= inv; qy *= inv; qz *= inv;

    float r00 = 1.0f - 2.0f * (qy * qy + qz * qz);
    float r01 = 2.0f * (qx * qy - qw * qz);
    float r02 = 2.0f * (qx * qz + qw * qy);
    float r10 = 2.0f * (qx * qy + qw * qz);
    float r11 = 1.0f - 2.0f * (qx * qx + qz * qz);
    float r12 = 2.0f * (qy * qz - qw * qx);
    float r20 = 2.0f * (qx * qz - qw * qy);
    float r21 = 2.0f * (qy * qz + qw * qx);
    float r22 = 1.0f - 2.0f * (qx * qx + qy * qy);

    float sx = scales[g * 3 + 0];
    float sy = scales[g * 3 + 1];
    float sz = scales[g * 3 + 2];
    float iv0 = 1.0f / (sx * sx);
    float iv1 = 1.0f / (sy * sy);
    float iv2 = 1.0f / (sz * sz);

    float a00 = iv0 * r00 * r00 + iv1 * r10 * r10 + iv2 * r20 * r20;
    float a01 = iv0 * r00 * r01 + iv1 * r10 * r11 + iv2 * r20 * r21;
    float a02 = iv0 * r00 * r02 + iv1 * r10 * r12 + iv2 * r20 * r22;
    float a11 = iv0 * r01 * r01 + iv1 * r11 * r11 + iv2 * r21 * r21;
    float a12 = iv0 * r01 * r02 + iv1 * r11 * r12 + iv2 * r21 * r22;
    float a22 = iv0 * r02 * r02 + iv1 * r12 * r12 + iv2 * r22 * r22;

    float mx = means[g * 3 + 0];
    float my = means[g * 3 + 1];
    float mz = means[g * 3 + 2];
    float amx = a00 * mx + a01 * my + a02 * mz;
    float amy = a01 * mx + a11 * my + a12 * mz;
    float amz = a02 * mx + a12 * my + a22 * mz;
    float muAmu = mx * amx + my * amy + mz * amz;

    const float k = -0.72134752044448170368f;   // -0.5 * log2(e)

    float* p = p2 + (size_t)g * P2_STRIDE;
    p[0] = k * a00;
    p[1] = k * a11;
    p[2] = k * a22;
    p[3] = 2.0f * k * a01;
    p[4] = 2.0f * k * a02;
    p[5] = 2.0f * k * a12;
    p[6] = -2.0f * k * amx;
    p[7] = -2.0f * k * amy;
    p[8] = -2.0f * k * amz;
    p[9] = k * muAmu + log2f(opacities[g]);

#pragma unroll
    for (int c = 0; c < N_CLASSES; ++c) {
        float v = semantics[g * N_CLASSES + c];
        _Float16 h = (_Float16)v;            // RNE, rel 2^-12
        float res = v - (float)h;            // exact
        semH[(size_t)c * N_GAUSS + g] = h;
        semL[(size_t)c * N_GAUSS + g] = (_Float16)res;
    }
}

// ---------------------------------------------------------------------------
// Main: 800 blocks (32 point-supergroups x 25 gaussian-splits) x 512 threads
// (8 waves), all co-resident (<=4 blocks/CU).
// KEY CHANGE vs R8: all 8 waves of a block iterate the SAME 128-gaussian
// split (wave wid owns points sg*512 + wid*64 .. +63). R8 gave every wave a
// DIFFERENT 100-gaussian range, so the CU's single scalar unit took
// correlated sL1 misses on 32 distinct coefficient streams -> all waves
// stalled together (VALUBusy ~24%). Now wave 0 warms sL1 and waves 1-7 hit;
// semH/semL B-frag loads are likewise block-shared (vL1 hits).
// Per chunk of 32 gaussians: lane (=point) computes w=exp2(arg) (9 FMA+exp,
// coeffs via wave-uniform s_loads), packs f16 RNE pairs, stages once in
// wave-private LDS (XOR-swizzled 16B blocks), 4 A-frag reads feed 8 MFMAs:
// w*semH + w*semL. Epilogue: wave owns its 64 output rows for this split ->
// direct fp32 atomics, NO LDS reduce, no __syncthreads.
// ---------------------------------------------------------------------------
__launch_bounds__(512, 4)
__global__ void gauss_occ_main_kernel(const float* __restrict__ xyz,
                                      const float* __restrict__ p2,
                                      const _Float16* __restrict__ semH,
                                      const _Float16* __restrict__ semL,
                                      float* __restrict__ out) {
    __shared__ unsigned int wbuf[8][64][16];   // 32 KiB: per-wave 4 KiB w-tile

    const int tid  = threadIdx.x;
    const int lane = tid & 63;
    const int wid  = __builtin_amdgcn_readfirstlane(tid >> 6);   // wave-uniform
    const int sg    = blockIdx.x / N_SPLITS;         // 0..31  point-supergroup
    const int split = blockIdx.x % N_SPLITS;         // 0..24  gaussian split
    const int gbase = split * G_PER_SPLIT;           // uniform across block!

    const int m   = lane & 15;      // fragment row/col id
    const int mm  = (m < N_CLASSES) ? m : (N_CLASSES - 1);  // B-row clamp
    const int grp = lane >> 4;      // k-group 0..3
    const int frs = (m >> 1) & 3;   // read-side swizzle
    const int wsz = (lane >> 1) & 3;// write-side swizzle

    const int ptb = sg * 512 + wid * 64;   // this wave's 64-point base
    const int pt  = ptb + lane;
    const float x = xyz[pt * 3 + 0];
    const float y = xyz[pt * 3 + 1];
    const float z = xyz[pt * 3 + 2];
    const float P0 = x * x, P1 = y * y, P2 = z * z;
    const float P3 = x * y, P4 = x * z, P5 = y * z;

    f32x4 acc0 = {0.f, 0.f, 0.f, 0.f};
    f32x4 acc1 = {0.f, 0.f, 0.f, 0.f};
    f32x4 acc2 = {0.f, 0.f, 0.f, 0.f};
    f32x4 acc3 = {0.f, 0.f, 0.f, 0.f};

    unsigned int (*wrow)[16] = wbuf[wid];

#pragma unroll
    for (int c = 0; c < G_PER_SPLIT / 32; ++c) {     // 4 chunks of 32 gaussians
        const int g0 = gbase + c * 32;   // uniform

        // B fragments: lane reads sem[clamped class][g0 + grp*8 .. +7]
        const half8 bH = *(const half8*)(semH + (size_t)mm * N_GAUSS + g0 + grp * 8);
        const half8 bL = *(const half8*)(semL + (size_t)mm * N_GAUSS + g0 + grp * 8);

        // ---- compute 32 w's, pack as f16 pairs (RNE) ----
        unsigned int wpk[16];
#pragma unroll
        for (int t = 0; t < 16; ++t) {
            const float* ga = p2 + (size_t)(g0 + 2 * t) * P2_STRIDE;  // uniform -> s_load
            const float* gb = ga + P2_STRIDE;
            float q0 = ga[9];
            q0 = fmaf(P0, ga[0], q0); q0 = fmaf(P1, ga[1], q0); q0 = fmaf(P2, ga[2], q0);
            q0 = fmaf(P3, ga[3], q0); q0 = fmaf(P4, ga[4], q0); q0 = fmaf(P5, ga[5], q0);
            q0 = fmaf(x,  ga[6], q0); q0 = fmaf(y,  ga[7], q0); q0 = fmaf(z,  ga[8], q0);
            float q1 = gb[9];
            q1 = fmaf(P0, gb[0], q1); q1 = fmaf(P1, gb[1], q1); q1 = fmaf(P2, gb[2], q1);
            q1 = fmaf(P3, gb[3], q1); q1 = fmaf(P4, gb[4], q1); q1 = fmaf(P5, gb[5], q1);
            q1 = fmaf(x,  gb[6], q1); q1 = fmaf(y,  gb[7], q1); q1 = fmaf(z,  gb[8], q1);
            half2v hv;
            hv[0] = (_Float16)__builtin_amdgcn_exp2f(q0);   // v_cvt_f16_f32 (RNE)
            hv[1] = (_Float16)__builtin_amdgcn_exp2f(q1);
            wpk[t] = __builtin_bit_cast(unsigned int, hv);
        }

        // ---- stage (once): row = lane, 16B block (sb ^ wsz) ----
#pragma unroll
        for (int sb = 0; sb < 4; ++sb) {
            *(uint4*)&wrow[lane][(sb ^ wsz) * 4] =
                make_uint4(wpk[4 * sb + 0], wpk[4 * sb + 1], wpk[4 * sb + 2], wpk[4 * sb + 3]);
        }

        // ---- A-frag reads + 8 MFMAs (compiler inserts precise lgkmcnt) ----
        const half8 a0 = *(const half8*)&wrow[ 0 + m][(grp ^ frs) * 4];
        const half8 a1 = *(const half8*)&wrow[16 + m][(grp ^ frs) * 4];
        const half8 a2 = *(const half8*)&wrow[32 + m][(grp ^ frs) * 4];
        const half8 a3 = *(const half8*)&wrow[48 + m][(grp ^ frs) * 4];
        acc0 = __builtin_amdgcn_mfma_f32_16x16x32_f16(a0, bH, acc0, 0, 0, 0);
        acc1 = __builtin_amdgcn_mfma_f32_16x16x32_f16(a1, bH, acc1, 0, 0, 0);
        acc2 = __builtin_amdgcn_mfma_f32_16x16x32_f16(a2, bH, acc2, 0, 0, 0);
        acc3 = __builtin_amdgcn_mfma_f32_16x16x32_f16(a3, bH, acc3, 0, 0, 0);
        acc0 = __builtin_amdgcn_mfma_f32_16x16x32_f16(a0, bL, acc0, 0, 0, 0);
        acc1 = __builtin_amdgcn_mfma_f32_16x16x32_f16(a1, bL, acc1, 0, 0, 0);
        acc2 = __builtin_amdgcn_mfma_f32_16x16x32_f16(a2, bL, acc2, 0, 0, 0);
        acc3 = __builtin_amdgcn_mfma_f32_16x16x32_f16(a3, bL, acc3, 0, 0, 0);
    }

    // ---- epilogue: direct atomic writes; D layout col=m(class),
    //      row = sub*16 + grp*4 + i (point within wave tile) ----
    if (m < N_CLASSES) {
#pragma unroll
        for (int i = 0; i < 4; ++i) {
            unsafeAtomicAdd(&out[(ptb +  0 + grp * 4 + i) * N_CLASSES + m], acc0[i]);
            unsafeAtomicAdd(&out[(ptb + 16 + grp * 4 + i) * N_CLASSES + m], acc1[i]);
            unsafeAtomicAdd(&out[(ptb + 32 + grp * 4 + i) * N_CLASSES + m], acc2[i]);
            unsafeAtomicAdd(&out[(ptb + 48 + grp * 4 + i) * N_CLASSES + m], acc3[i]);
        }
    }
}

extern "C" void kernel_launch(void* const* d_in, const int* in_sizes, int n_in,
                              void* d_out, int out_size, void* d_ws, size_t ws_size,
                              hipStream_t stream) {
    const float* xyz       = (const float*)d_in[0];
    const float* means     = (const float*)d_in[1];
    const float* scales    = (const float*)d_in[2];
    const float* rotations = (const float*)d_in[3];
    const float* opacities = (const float*)d_in[4];
    const float* semantics = (const float*)d_in[5];
    float* out = (float*)d_out;

    float*    p2   = (float*)((char*)d_ws + WS_P2_OFF);
    _Float16* semH = (_Float16*)((char*)d_ws + WS_SEMH_OFF);
    _Float16* semL = (_Float16*)((char*)d_ws + WS_SEML_OFF);

    (void)hipMemsetAsync(d_out, 0, (size_t)out_size * sizeof(float), stream);

    hipLaunchKernelGGL(gauss_prep_kernel,
                       dim3((N_GAUSS + 255) / 256), dim3(256), 0, stream,
                       means, scales, rotations, opacities, semantics, p2, semH, semL);

    hipLaunchKernelGGL(gauss_occ_main_kernel,
                       dim3(N_SG * N_SPLITS), dim3(512), 0, stream,
                       xyz, p2, semH, semL, out);
}

// Round 10
// 25.407 us; speedup vs baseline: 2.5137x; 2.5137x over previous
//
#include <hip/hip_runtime.h>
#include <hip/hip_bf16.h>

#define N_POINTS 16384
#define N_GAUSS  3200
#define N_CLASSES 14
#define NCHUNK (N_GAUSS / 32)   // 100 chunks of 32 gaussians

typedef _Float16 half8  __attribute__((ext_vector_type(8)));   // 4 VGPRs
typedef _Float16 half2v __attribute__((ext_vector_type(2)));
typedef float    f32x4  __attribute__((ext_vector_type(4)));

// d_ws layout (294,400 B <= proven-safe 307,200):
//   [0, 204800)        crec: [3200][32] f16  -- slots 0..9=Ch, 10..15=0,
//                                               16..25=Cl, 26..31=0
//   [204800, 294400)   semP: [14][3200] f16  -- chunk-permuted semantics
#define WS_CREC_OFF 0
#define WS_SEMP_OFF 204800

// ---------------------------------------------------------------------------
// Prep. C[10] quadratic-form coefficients (P-form):
//   arg = Sum_k P[k]*C[k],  P = [x^2,y^2,z^2,xy,xz,yz,x,y,z,1]
//   exp2(arg) = opacity * exp(-0.5*q)
// Stored as f16 hi+lo record (32 slots) for the Q-MFMA A-fragment.
// Semantics f16, permuted to the PV K-order: within chunk c, position
// p = grpW*8 + gt*4 + i  <->  g = c*32 + gt*16 + grpW*4 + i.
// ---------------------------------------------------------------------------
__global__ void gauss_prep_kernel(const float* __restrict__ means,
                                  const float* __restrict__ scales,
                                  const float* __restrict__ rotations,
                                  const float* __restrict__ opacities,
                                  const float* __restrict__ semantics,
                                  _Float16* __restrict__ crec,
                                  _Float16* __restrict__ semP) {
    int g = blockIdx.x * blockDim.x + threadIdx.x;
    if (g >= N_GAUSS) return;

    float qw = rotations[g * 4 + 0];
    float qx = rotations[g * 4 + 1];
    float qy = rotations[g * 4 + 2];
    float qz = rotations[g * 4 + 3];
    float inv = 1.0f / sqrtf(qw * qw + qx * qx + qy * qy + qz * qz);
    qw *= inv; qx *= inv; qy *= inv; qz *= inv;

    float r00 = 1.0f - 2.0f * (qy * qy + qz * qz);
    float r01 = 2.0f * (qx * qy - qw * qz);
    float r02 = 2.0f * (qx * qz + qw * qy);
    float r10 = 2.0f * (qx * qy + qw * qz);
    float r11 = 1.0f - 2.0f * (qx * qx + qz * qz);
    float r12 = 2.0f * (qy * qz - qw * qx);
    float r20 = 2.0f * (qx * qz - qw * qy);
    float r21 = 2.0f * (qy * qz + qw * qx);
    float r22 = 1.0f - 2.0f * (qx * qx + qy * qy);

    float sx = scales[g * 3 + 0];
    float sy = scales[g * 3 + 1];
    float sz = scales[g * 3 + 2];
    float iv0 = 1.0f / (sx * sx);
    float iv1 = 1.0f / (sy * sy);
    float iv2 = 1.0f / (sz * sz);

    float a00 = iv0 * r00 * r00 + iv1 * r10 * r10 + iv2 * r20 * r20;
    float a01 = iv0 * r00 * r01 + iv1 * r10 * r11 + iv2 * r20 * r21;
    float a02 = iv0 * r00 * r02 + iv1 * r10 * r12 + iv2 * r20 * r22;
    float a11 = iv0 * r01 * r01 + iv1 * r11 * r11 + iv2 * r21 * r21;
    float a12 = iv0 * r01 * r02 + iv1 * r11 * r12 + iv2 * r21 * r22;
    float a22 = iv0 * r02 * r02 + iv1 * r12 * r12 + iv2 * r22 * r22;

    float mx = means[g * 3 + 0];
    float my = means[g * 3 + 1];
    float mz = means[g * 3 + 2];
    float amx = a00 * mx + a01 * my + a02 * mz;
    float amy = a01 * mx + a11 * my + a12 * mz;
    float amz = a02 * mx + a12 * my + a22 * mz;
    float muAmu = mx * amx + my * amy + mz * amz;

    const float k = -0.72134752044448170368f;   // -0.5 * log2(e)

    float C[10];
    C[0] = k * a00;  C[1] = k * a11;  C[2] = k * a22;
    C[3] = 2.0f * k * a01;  C[4] = 2.0f * k * a02;  C[5] = 2.0f * k * a12;
    C[6] = -2.0f * k * amx; C[7] = -2.0f * k * amy; C[8] = -2.0f * k * amz;
    C[9] = k * muAmu + log2f(opacities[g]);

    _Float16* rec = crec + (size_t)g * 32;
#pragma unroll
    for (int kk = 0; kk < 10; ++kk) {
        _Float16 h = (_Float16)C[kk];
        rec[kk]      = h;
        rec[16 + kk] = (_Float16)(C[kk] - (float)h);   // exact residual
    }
#pragma unroll
    for (int kk = 10; kk < 16; ++kk) { rec[kk] = (_Float16)0; rec[16 + kk] = (_Float16)0; }

    const int cidx = g >> 5, r = g & 31;
    const int gt = r >> 4, grpW = (r >> 2) & 3, i = r & 3;
    const int p = grpW * 8 + gt * 4 + i;
#pragma unroll
    for (int c = 0; c < N_CLASSES; ++c)
        semP[(size_t)c * N_GAUSS + cidx * 32 + p] = (_Float16)semantics[g * N_CLASSES + c];
}

// ---------------------------------------------------------------------------
// Main: 1024 blocks (256 point-groups x 4 splits) x 512 threads (R8's proven
// grid + LDS-reduce epilogue). Wave slot = split*8+wid owns 3-4 chunks.
// Per chunk (64 pts x 32 g), q is computed ON THE MATRIX PIPE:
//   Q-phase: D[g][pt] = Crec . Pfrag via 16 MFMAs (f16 3-term hi/lo:
//     [Ch|Cl]*[Ph;Ph] + [Ch|Cl]*[Pl;0] -- A-record reused, B-frags pinned
//     in VGPRs from a one-time LDS exchange of per-point monomials).
//   Then exp2 on D-frags (lane-local), cvt_pk pairs, ONE b128 LDS write per
//   s-tile (K-order p = grp*8+gt*4+i makes lane's 8 w's contiguous; semP is
//   pre-permuted to match), swizzled with the proven 0-conflict pattern.
//   PV-phase: 4 A-frag b128 reads + 4 MFMAs vs semP B-frag.
// This removes the ~370-VALU/chunk scalar q loop (R7-R9's 25-30% issue wall)
// and all SMEM coefficient traffic (Crec loads are coalesced per-lane VMEM).
// ---------------------------------------------------------------------------
__launch_bounds__(512, 4)
__global__ void gauss_occ_main_kernel(const float* __restrict__ xyz,
                                      const _Float16* __restrict__ crec,
                                      const _Float16* __restrict__ semP,
                                      float* __restrict__ out) {
    __shared__ unsigned int wbuf[8][64][16];   // 32 KiB: per-wave 4 KiB tile

    const int tid  = threadIdx.x;
    const int lane = tid & 63;
    const int wid  = __builtin_amdgcn_readfirstlane(tid >> 6);
    const int pg    = blockIdx.x >> 2;
    const int split = blockIdx.x & 3;
    const int slot  = split * 8 + wid;
    const int c0 = (slot * NCHUNK) >> 5;
    const int c1 = ((slot + 1) * NCHUNK) >> 5;

    const int m   = lane & 15;
    const int mm  = (m < N_CLASSES) ? m : (N_CLASSES - 1);
    const int grp = lane >> 4;
    const int swz = (m >> 1) & 3;          // 16B-block swizzle key (rows s*16+m)

    const int pt = pg * 64 + lane;
    const float x = xyz[pt * 3 + 0];
    const float y = xyz[pt * 3 + 1];
    const float z = xyz[pt * 3 + 2];

    unsigned int (*wrow)[16] = wbuf[wid];

    // ---- one-time: stage per-point monomials, gather Q B-fragments ----
    {
        float P[10] = {x * x, y * y, z * z, x * y, x * z, y * z, x, y, z, 1.0f};
        half8 ph0, ph1, pl0, pl1;
#pragma unroll
        for (int j = 0; j < 8; ++j) {
            _Float16 h = (_Float16)P[j];
            ph0[j] = h; pl0[j] = (_Float16)(P[j] - (float)h);
            ph1[j] = (_Float16)0; pl1[j] = (_Float16)0;
        }
#pragma unroll
        for (int j = 0; j < 2; ++j) {
            _Float16 h = (_Float16)P[8 + j];
            ph1[j] = h; pl1[j] = (_Float16)(P[8 + j] - (float)h);
        }
        *(half8*)&wrow[lane][ 0] = ph0;
        *(half8*)&wrow[lane][ 4] = ph1;
        *(half8*)&wrow[lane][ 8] = pl0;
        *(half8*)&wrow[lane][12] = pl1;
    }

    half8 f1[4], f2[4];
    {
        half8 fz;
#pragma unroll
        for (int j = 0; j < 8; ++j) fz[j] = (_Float16)0;
#pragma unroll
        for (int s = 0; s < 4; ++s) {
            f1[s] = *(const half8*)&wrow[s * 16 + m][(grp & 1) * 4];
            f2[s] = (grp < 2) ? *(const half8*)&wrow[s * 16 + m][8 + (grp & 1) * 4] : fz;
        }
    }

    f32x4 acc0 = {0.f, 0.f, 0.f, 0.f};
    f32x4 acc1 = {0.f, 0.f, 0.f, 0.f};
    f32x4 acc2 = {0.f, 0.f, 0.f, 0.f};
    f32x4 acc3 = {0.f, 0.f, 0.f, 0.f};
    const f32x4 z4 = {0.f, 0.f, 0.f, 0.f};

    for (int c = c0; c < c1; ++c) {
        // A-records (Q-phase): gauss g = c*32 + gt*16 + m, 16B per lane
        const size_t rbase = ((size_t)(c * 32 + m)) * 32 + grp * 8;
        const half8 A0 = *(const half8*)(crec + rbase);            // gt = 0
        const half8 A1 = *(const half8*)(crec + rbase + 16 * 32);  // gt = 1
        // B-fragment (PV-phase): permuted semantics, 16B contiguous
        const half8 bS = *(const half8*)(semP + (size_t)mm * N_GAUSS + c * 32 + grp * 8);

        // ---- Q-MFMAs + exp + pack + staged write, per point-tile s ----
#pragma unroll
        for (int s = 0; s < 4; ++s) {
            f32x4 t0 = __builtin_amdgcn_mfma_f32_16x16x32_f16(A0, f1[s], z4, 0, 0, 0);
            t0       = __builtin_amdgcn_mfma_f32_16x16x32_f16(A0, f2[s], t0, 0, 0, 0);
            f32x4 t1 = __builtin_amdgcn_mfma_f32_16x16x32_f16(A1, f1[s], z4, 0, 0, 0);
            t1       = __builtin_amdgcn_mfma_f32_16x16x32_f16(A1, f2[s], t1, 0, 0, 0);

            half2v h01, h23, h45, h67;
            h01[0] = (_Float16)__builtin_amdgcn_exp2f(t0[0]);
            h01[1] = (_Float16)__builtin_amdgcn_exp2f(t0[1]);
            h23[0] = (_Float16)__builtin_amdgcn_exp2f(t0[2]);
            h23[1] = (_Float16)__builtin_amdgcn_exp2f(t0[3]);
            h45[0] = (_Float16)__builtin_amdgcn_exp2f(t1[0]);
            h45[1] = (_Float16)__builtin_amdgcn_exp2f(t1[1]);
            h67[0] = (_Float16)__builtin_amdgcn_exp2f(t1[2]);
            h67[1] = (_Float16)__builtin_amdgcn_exp2f(t1[3]);

            *(uint4*)&wrow[s * 16 + m][(grp ^ swz) * 4] =
                make_uint4(__builtin_bit_cast(unsigned int, h01),
                           __builtin_bit_cast(unsigned int, h23),
                           __builtin_bit_cast(unsigned int, h45),
                           __builtin_bit_cast(unsigned int, h67));
        }

        // ---- PV-phase: A-frag reads + 4 MFMAs ----
        const half8 a0 = *(const half8*)&wrow[ 0 + m][(grp ^ swz) * 4];
        const half8 a1 = *(const half8*)&wrow[16 + m][(grp ^ swz) * 4];
        const half8 a2 = *(const half8*)&wrow[32 + m][(grp ^ swz) * 4];
        const half8 a3 = *(const half8*)&wrow[48 + m][(grp ^ swz) * 4];
        acc0 = __builtin_amdgcn_mfma_f32_16x16x32_f16(a0, bS, acc0, 0, 0, 0);
        acc1 = __builtin_amdgcn_mfma_f32_16x16x32_f16(a1, bS, acc1, 0, 0, 0);
        acc2 = __builtin_amdgcn_mfma_f32_16x16x32_f16(a2, bS, acc2, 0, 0, 0);
        acc3 = __builtin_amdgcn_mfma_f32_16x16x32_f16(a3, bS, acc3, 0, 0, 0);
    }

    // ---- epilogue (R8): dump acc into own LDS region, 8-way reduce ----
    float* red = (float*)&wbuf[0][0][0];
#pragma unroll
    for (int i = 0; i < 4; ++i) {
        red[wid * 1024 + ( 0 + grp * 4 + i) * 16 + m] = acc0[i];
        red[wid * 1024 + (16 + grp * 4 + i) * 16 + m] = acc1[i];
        red[wid * 1024 + (32 + grp * 4 + i) * 16 + m] = acc2[i];
        red[wid * 1024 + (48 + grp * 4 + i) * 16 + m] = acc3[i];
    }
    __syncthreads();

    for (int idx = tid; idx < 64 * N_CLASSES; idx += 512) {
        const int l = idx / N_CLASSES;
        const int cc = idx - l * N_CLASSES;
        float s = 0.0f;
#pragma unroll
        for (int wq = 0; wq < 8; ++wq) s += red[wq * 1024 + l * 16 + cc];
        unsafeAtomicAdd(&out[(pg * 64 + l) * N_CLASSES + cc], s);
    }
}

extern "C" void kernel_launch(void* const* d_in, const int* in_sizes, int n_in,
                              void* d_out, int out_size, void* d_ws, size_t ws_size,
                              hipStream_t stream) {
    const float* xyz       = (const float*)d_in[0];
    const float* means     = (const float*)d_in[1];
    const float* scales    = (const float*)d_in[2];
    const float* rotations = (const float*)d_in[3];
    const float* opacities = (const float*)d_in[4];
    const float* semantics = (const float*)d_in[5];
    float* out = (float*)d_out;

    _Float16* crec = (_Float16*)((char*)d_ws + WS_CREC_OFF);
    _Float16* semP = (_Float16*)((char*)d_ws + WS_SEMP_OFF);

    (void)hipMemsetAsync(d_out, 0, (size_t)out_size * sizeof(float), stream);

    hipLaunchKernelGGL(gauss_prep_kernel,
                       dim3((N_GAUSS + 255) / 256), dim3(256), 0, stream,
                       means, scales, rotations, opacities, semantics, crec, semP);

    hipLaunchKernelGGL(gauss_occ_main_kernel,
                       dim3(256 * 4), dim3(512), 0, stream,
                       xyz, crec, semP, out);
}

// Round 11
// 21.244 us; speedup vs baseline: 3.0062x; 1.1959x over previous
//
#include <hip/hip_runtime.h>
#include <hip/hip_bf16.h>

#define N_POINTS 16384
#define N_GAUSS  3200
#define N_CLASSES 14
#define NCHUNK (N_GAUSS / 32)   // 100 chunks of 32 gaussians

typedef _Float16 half8  __attribute__((ext_vector_type(8)));   // 4 VGPRs
typedef _Float16 half2v __attribute__((ext_vector_type(2)));
typedef float    f32x4  __attribute__((ext_vector_type(4)));

// d_ws layout (294,400 B <= proven-safe 307,200):
//   [0, 204800)        crec: [3200][32] f16 -- K-slots [Ch(10)|Cl(10)|Ch(10)|0,0]
//   [204800, 294400)   semP: [14][3200] f16 -- chunk-permuted semantics
#define WS_CREC_OFF 0
#define WS_SEMP_OFF 204800

// ---------------------------------------------------------------------------
// Prep. C[10] quadratic-form coefficients (P-form):
//   arg = Sum_k P[k]*C[k],  P = [x^2,y^2,z^2,xy,xz,yz,x,y,z,1]
//   exp2(arg) = opacity * exp(-0.5*q)
// K=32 record packs ALL THREE precision terms of one contraction:
//   A = [Ch|Cl|Ch|00] x B = [Ph|Ph|Pl|00] -> Ch.Ph + Cl.Ph + Ch.Pl
// (one Q-MFMA per A/B pair instead of R10's two).
// Semantics f16, permuted to PV K-order: p = grpW*8 + gt*4 + i <->
// g = c*32 + gt*16 + grpW*4 + i.
// Also zeroes d_out (grid-stride) so no separate memset dispatch is needed.
// ---------------------------------------------------------------------------
__global__ void gauss_prep_kernel(const float* __restrict__ means,
                                  const float* __restrict__ scales,
                                  const float* __restrict__ rotations,
                                  const float* __restrict__ opacities,
                                  const float* __restrict__ semantics,
                                  _Float16* __restrict__ crec,
                                  _Float16* __restrict__ semP,
                                  float* __restrict__ out) {
    const int gid = blockIdx.x * blockDim.x + threadIdx.x;   // 0..16383

    // zero d_out: 229,376 floats / 16,384 threads = 14 coalesced rounds
#pragma unroll
    for (int i = 0; i < N_CLASSES; ++i)
        out[i * N_POINTS + gid] = 0.0f;   // 14 * 16384 == N_POINTS*N_CLASSES

    const int g = gid;
    if (g >= N_GAUSS) return;

    float qw = rotations[g * 4 + 0];
    float qx = rotations[g * 4 + 1];
    float qy = rotations[g * 4 + 2];
    float qz = rotations[g * 4 + 3];
    float inv = 1.0f / sqrtf(qw * qw + qx * qx + qy * qy + qz * qz);
    qw *= inv; qx *= inv; qy *= inv; qz *= inv;

    float r00 = 1.0f - 2.0f * (qy * qy + qz * qz);
    float r01 = 2.0f * (qx * qy - qw * qz);
    float r02 = 2.0f * (qx * qz + qw * qy);
    float r10 = 2.0f * (qx * qy + qw * qz);
    float r11 = 1.0f - 2.0f * (qx * qx + qz * qz);
    float r12 = 2.0f * (qy * qz - qw * qx);
    float r20 = 2.0f * (qx * qz - qw * qy);
    float r21 = 2.0f * (qy * qz + qw * qx);
    float r22 = 1.0f - 2.0f * (qx * qx + qy * qy);

    float sx = scales[g * 3 + 0];
    float sy = scales[g * 3 + 1];
    float sz = scales[g * 3 + 2];
    float iv0 = 1.0f / (sx * sx);
    float iv1 = 1.0f / (sy * sy);
    float iv2 = 1.0f / (sz * sz);

    float a00 = iv0 * r00 * r00 + iv1 * r10 * r10 + iv2 * r20 * r20;
    float a01 = iv0 * r00 * r01 + iv1 * r10 * r11 + iv2 * r20 * r21;
    float a02 = iv0 * r00 * r02 + iv1 * r10 * r12 + iv2 * r20 * r22;
    float a11 = iv0 * r01 * r01 + iv1 * r11 * r11 + iv2 * r21 * r21;
    float a12 = iv0 * r01 * r02 + iv1 * r11 * r12 + iv2 * r21 * r22;
    float a22 = iv0 * r02 * r02 + iv1 * r12 * r12 + iv2 * r22 * r22;

    float mx = means[g * 3 + 0];
    float my = means[g * 3 + 1];
    float mz = means[g * 3 + 2];
    float amx = a00 * mx + a01 * my + a02 * mz;
    float amy = a01 * mx + a11 * my + a12 * mz;
    float amz = a02 * mx + a12 * my + a22 * mz;
    float muAmu = mx * amx + my * amy + mz * amz;

    const float k = -0.72134752044448170368f;   // -0.5 * log2(e)

    float C[10];
    C[0] = k * a00;  C[1] = k * a11;  C[2] = k * a22;
    C[3] = 2.0f * k * a01;  C[4] = 2.0f * k * a02;  C[5] = 2.0f * k * a12;
    C[6] = -2.0f * k * amx; C[7] = -2.0f * k * amy; C[8] = -2.0f * k * amz;
    C[9] = k * muAmu + log2f(opacities[g]);

    _Float16* rec = crec + (size_t)g * 32;
#pragma unroll
    for (int kk = 0; kk < 10; ++kk) {
        _Float16 h = (_Float16)C[kk];
        rec[kk]      = h;                              // Ch at K 0..9
        rec[10 + kk] = (_Float16)(C[kk] - (float)h);   // Cl at K 10..19
        rec[20 + kk] = h;                              // Ch again at K 20..29
    }
    rec[30] = (_Float16)0; rec[31] = (_Float16)0;

    const int cidx = g >> 5, r = g & 31;
    const int gt = r >> 4, grpW = (r >> 2) & 3, i = r & 3;
    const int p = grpW * 8 + gt * 4 + i;
#pragma unroll
    for (int c = 0; c < N_CLASSES; ++c)
        semP[(size_t)c * N_GAUSS + cidx * 32 + p] = (_Float16)semantics[g * N_CLASSES + c];
}

// ---------------------------------------------------------------------------
// Main: 1024 blocks (256 point-groups x 4 splits) x 512 threads.
// Per chunk (64 pts x 32 g):
//   Q-phase: D[g][pt] = Crec . Brow via 2 MFMAs per point-subtile (8/chunk;
//     R10 needed 16 -- the [Ch|Cl|Ch]x[Ph|Ph|Pl] K-packing fuses the 3-term
//     hi/lo product into ONE K=32 contraction).
//   exp2 on D-frags (lane-local), cvt_pk pairs, one swizzled b128 LDS write
//   per s-tile, then PV-phase: 4 A-frag reads + 4 MFMAs vs semP.
// Epilogue: LDS 8-way reduce + one fp32 atomic per element.
// ---------------------------------------------------------------------------
__launch_bounds__(512, 4)
__global__ void gauss_occ_main_kernel(const float* __restrict__ xyz,
                                      const _Float16* __restrict__ crec,
                                      const _Float16* __restrict__ semP,
                                      float* __restrict__ out) {
    __shared__ unsigned int wbuf[8][64][16];   // 32 KiB: per-wave 4 KiB tile

    const int tid  = threadIdx.x;
    const int lane = tid & 63;
    const int wid  = __builtin_amdgcn_readfirstlane(tid >> 6);
    const int pg    = blockIdx.x >> 2;
    const int split = blockIdx.x & 3;
    const int slot  = split * 8 + wid;
    const int c0 = (slot * NCHUNK) >> 5;
    const int c1 = ((slot + 1) * NCHUNK) >> 5;

    const int m   = lane & 15;
    const int mm  = (m < N_CLASSES) ? m : (N_CLASSES - 1);
    const int grp = lane >> 4;
    const int frs = (m >> 1) & 3;          // swizzle key for rows s*16+m
    const int wsz = (lane >> 1) & 3;       // swizzle key for row lane

    const int pt = pg * 64 + lane;
    const float x = xyz[pt * 3 + 0];
    const float y = xyz[pt * 3 + 1];
    const float z = xyz[pt * 3 + 2];

    unsigned int (*wrow)[16] = wbuf[wid];

    // ---- one-time: stage expanded 32-slot B-row [Ph|Ph|Pl|00] per point ----
    {
        float P[10] = {x * x, y * y, z * z, x * y, x * z, y * z, x, y, z, 1.0f};
        _Float16 Ph[10], Pl[10];
#pragma unroll
        for (int j = 0; j < 10; ++j) {
            Ph[j] = (_Float16)P[j];
            Pl[j] = (_Float16)(P[j] - (float)Ph[j]);   // exact residual
        }
        half8 b0, b1, b2, b3;
#pragma unroll
        for (int j = 0; j < 8; ++j) b0[j] = Ph[j];                 // K0-7
        b1[0] = Ph[8]; b1[1] = Ph[9];
#pragma unroll
        for (int j = 0; j < 6; ++j) b1[2 + j] = Ph[j];             // K8-15
#pragma unroll
        for (int j = 0; j < 4; ++j) { b2[j] = Ph[6 + j]; b2[4 + j] = Pl[j]; }  // K16-23
#pragma unroll
        for (int j = 0; j < 6; ++j) b3[j] = Pl[4 + j];             // K24-29
        b3[6] = (_Float16)0; b3[7] = (_Float16)0;                  // K30-31
        *(half8*)&wrow[lane][(0 ^ wsz) * 4] = b0;
        *(half8*)&wrow[lane][(1 ^ wsz) * 4] = b1;
        *(half8*)&wrow[lane][(2 ^ wsz) * 4] = b2;
        *(half8*)&wrow[lane][(3 ^ wsz) * 4] = b3;
    }

    // gather Q B-fragments: lane (m,grp) needs block grp of point s*16+m
    half8 f1[4];
#pragma unroll
    for (int s = 0; s < 4; ++s)
        f1[s] = *(const half8*)&wrow[s * 16 + m][(grp ^ frs) * 4];

    f32x4 acc0 = {0.f, 0.f, 0.f, 0.f};
    f32x4 acc1 = {0.f, 0.f, 0.f, 0.f};
    f32x4 acc2 = {0.f, 0.f, 0.f, 0.f};
    f32x4 acc3 = {0.f, 0.f, 0.f, 0.f};
    const f32x4 z4 = {0.f, 0.f, 0.f, 0.f};

    for (int c = c0; c < c1; ++c) {
        // A-records (Q-phase): gauss g = c*32 + gt*16 + m, 16B per lane
        const size_t rbase = ((size_t)(c * 32 + m)) * 32 + grp * 8;
        const half8 A0 = *(const half8*)(crec + rbase);            // gt = 0
        const half8 A1 = *(const half8*)(crec + rbase + 16 * 32);  // gt = 1
        // B-fragment (PV-phase): permuted semantics, 16B contiguous
        const half8 bS = *(const half8*)(semP + (size_t)mm * N_GAUSS + c * 32 + grp * 8);

        // ---- Q-MFMAs + exp + pack + staged write, per point-subtile s ----
#pragma unroll
        for (int s = 0; s < 4; ++s) {
            f32x4 t0 = __builtin_amdgcn_mfma_f32_16x16x32_f16(A0, f1[s], z4, 0, 0, 0);
            f32x4 t1 = __builtin_amdgcn_mfma_f32_16x16x32_f16(A1, f1[s], z4, 0, 0, 0);

            half2v h01, h23, h45, h67;
            h01[0] = (_Float16)__builtin_amdgcn_exp2f(t0[0]);
            h01[1] = (_Float16)__builtin_amdgcn_exp2f(t0[1]);
            h23[0] = (_Float16)__builtin_amdgcn_exp2f(t0[2]);
            h23[1] = (_Float16)__builtin_amdgcn_exp2f(t0[3]);
            h45[0] = (_Float16)__builtin_amdgcn_exp2f(t1[0]);
            h45[1] = (_Float16)__builtin_amdgcn_exp2f(t1[1]);
            h67[0] = (_Float16)__builtin_amdgcn_exp2f(t1[2]);
            h67[1] = (_Float16)__builtin_amdgcn_exp2f(t1[3]);

            *(uint4*)&wrow[s * 16 + m][(grp ^ frs) * 4] =
                make_uint4(__builtin_bit_cast(unsigned int, h01),
                           __builtin_bit_cast(unsigned int, h23),
                           __builtin_bit_cast(unsigned int, h45),
                           __builtin_bit_cast(unsigned int, h67));
        }

        // ---- PV-phase: A-frag reads + 4 MFMAs ----
        const half8 a0 = *(const half8*)&wrow[ 0 + m][(grp ^ frs) * 4];
        const half8 a1 = *(const half8*)&wrow[16 + m][(grp ^ frs) * 4];
        const half8 a2 = *(const half8*)&wrow[32 + m][(grp ^ frs) * 4];
        const half8 a3 = *(const half8*)&wrow[48 + m][(grp ^ frs) * 4];
        acc0 = __builtin_amdgcn_mfma_f32_16x16x32_f16(a0, bS, acc0, 0, 0, 0);
        acc1 = __builtin_amdgcn_mfma_f32_16x16x32_f16(a1, bS, acc1, 0, 0, 0);
        acc2 = __builtin_amdgcn_mfma_f32_16x16x32_f16(a2, bS, acc2, 0, 0, 0);
        acc3 = __builtin_amdgcn_mfma_f32_16x16x32_f16(a3, bS, acc3, 0, 0, 0);
    }

    // ---- epilogue: dump acc into own LDS region, 8-way reduce, atomics ----
    float* red = (float*)&wbuf[0][0][0];
#pragma unroll
    for (int i = 0; i < 4; ++i) {
        red[wid * 1024 + ( 0 + grp * 4 + i) * 16 + m] = acc0[i];
        red[wid * 1024 + (16 + grp * 4 + i) * 16 + m] = acc1[i];
        red[wid * 1024 + (32 + grp * 4 + i) * 16 + m] = acc2[i];
        red[wid * 1024 + (48 + grp * 4 + i) * 16 + m] = acc3[i];
    }
    __syncthreads();

    for (int idx = tid; idx < 64 * N_CLASSES; idx += 512) {
        const int l = idx / N_CLASSES;
        const int cc = idx - l * N_CLASSES;
        float s = 0.0f;
#pragma unroll
        for (int wq = 0; wq < 8; ++wq) s += red[wq * 1024 + l * 16 + cc];
        unsafeAtomicAdd(&out[(pg * 64 + l) * N_CLASSES + cc], s);
    }
}

extern "C" void kernel_launch(void* const* d_in, const int* in_sizes, int n_in,
                              void* d_out, int out_size, void* d_ws, size_t ws_size,
                              hipStream_t stream) {
    const float* xyz       = (const float*)d_in[0];
    const float* means     = (const float*)d_in[1];
    const float* scales    = (const float*)d_in[2];
    const float* rotations = (const float*)d_in[3];
    const float* opacities = (const float*)d_in[4];
    const float* semantics = (const float*)d_in[5];
    float* out = (float*)d_out;

    _Float16* crec = (_Float16*)((char*)d_ws + WS_CREC_OFF);
    _Float16* semP = (_Float16*)((char*)d_ws + WS_SEMP_OFF);

    // prep zeroes d_out itself (16384 threads); no memset dispatch.
    hipLaunchKernelGGL(gauss_prep_kernel,
                       dim3(64), dim3(256), 0, stream,
                       means, scales, rotations, opacities, semantics, crec, semP, out);

    hipLaunchKernelGGL(gauss_occ_main_kernel,
                       dim3(256 * 4), dim3(512), 0, stream,
                       xyz, crec, semP, out);
}

// Round 12
// 19.454 us; speedup vs baseline: 3.2828x; 1.0920x over previous
//
#include <hip/hip_runtime.h>
#include <hip/hip_bf16.h>

#define N_POINTS 16384
#define N_GAUSS  3200
#define N_CLASSES 14
#define NCHUNK (N_GAUSS / 32)   // 100 chunks of 32 gaussians

typedef _Float16 half8  __attribute__((ext_vector_type(8)));   // 4 VGPRs
typedef _Float16 half2v __attribute__((ext_vector_type(2)));
typedef float    f32x4  __attribute__((ext_vector_type(4)));

// d_ws layout (294,400 B <= proven-safe 307,200):
//   [0, 204800)        crec: [3200][32] f16 -- K-slots [Ch(10)|Cl(10)|Ch(10)|0,0]
//   [204800, 294400)   semP: [14][3200] f16 -- chunk-permuted semantics
#define WS_CREC_OFF 0
#define WS_SEMP_OFF 204800

// ---------------------------------------------------------------------------
// Prep. C[10] quadratic-form coefficients (P-form):
//   arg = Sum_k P[k]*C[k],  P = [x^2,y^2,z^2,xy,xz,yz,x,y,z,1]
//   exp2(arg) = opacity * exp(-0.5*q)
// K=32 record packs all three precision terms of one contraction:
//   A = [Ch|Cl|Ch|00] x B = [Ph|Ph|Pl|00] -> Ch.Ph + Cl.Ph + Ch.Pl
// Semantics f16, permuted to PV K-order: p = grpW*8 + gt*4 + i <->
// g = c*32 + gt*16 + grpW*4 + i.
// ---------------------------------------------------------------------------
__global__ void gauss_prep_kernel(const float* __restrict__ means,
                                  const float* __restrict__ scales,
                                  const float* __restrict__ rotations,
                                  const float* __restrict__ opacities,
                                  const float* __restrict__ semantics,
                                  _Float16* __restrict__ crec,
                                  _Float16* __restrict__ semP) {
    const int g = blockIdx.x * blockDim.x + threadIdx.x;
    if (g >= N_GAUSS) return;

    float qw = rotations[g * 4 + 0];
    float qx = rotations[g * 4 + 1];
    float qy = rotations[g * 4 + 2];
    float qz = rotations[g * 4 + 3];
    float inv = 1.0f / sqrtf(qw * qw + qx * qx + qy * qy + qz * qz);
    qw *= inv; qx *= inv; qy *= inv; qz *= inv;

    float r00 = 1.0f - 2.0f * (qy * qy + qz * qz);
    float r01 = 2.0f * (qx * qy - qw * qz);
    float r02 = 2.0f * (qx * qz + qw * qy);
    float r10 = 2.0f * (qx * qy + qw * qz);
    float r11 = 1.0f - 2.0f * (qx * qx + qz * qz);
    float r12 = 2.0f * (qy * qz - qw * qx);
    float r20 = 2.0f * (qx * qz - qw * qy);
    float r21 = 2.0f * (qy * qz + qw * qx);
    float r22 = 1.0f - 2.0f * (qx * qx + qy * qy);

    float sx = scales[g * 3 + 0];
    float sy = scales[g * 3 + 1];
    float sz = scales[g * 3 + 2];
    float iv0 = 1.0f / (sx * sx);
    float iv1 = 1.0f / (sy * sy);
    float iv2 = 1.0f / (sz * sz);

    float a00 = iv0 * r00 * r00 + iv1 * r10 * r10 + iv2 * r20 * r20;
    float a01 = iv0 * r00 * r01 + iv1 * r10 * r11 + iv2 * r20 * r21;
    float a02 = iv0 * r00 * r02 + iv1 * r10 * r12 + iv2 * r20 * r22;
    float a11 = iv0 * r01 * r01 + iv1 * r11 * r11 + iv2 * r21 * r21;
    float a12 = iv0 * r01 * r02 + iv1 * r11 * r12 + iv2 * r21 * r22;
    float a22 = iv0 * r02 * r02 + iv1 * r12 * r12 + iv2 * r22 * r22;

    float mx = means[g * 3 + 0];
    float my = means[g * 3 + 1];
    float mz = means[g * 3 + 2];
    float amx = a00 * mx + a01 * my + a02 * mz;
    float amy = a01 * mx + a11 * my + a12 * mz;
    float amz = a02 * mx + a12 * my + a22 * mz;
    float muAmu = mx * amx + my * amy + mz * amz;

    const float k = -0.72134752044448170368f;   // -0.5 * log2(e)

    float C[10];
    C[0] = k * a00;  C[1] = k * a11;  C[2] = k * a22;
    C[3] = 2.0f * k * a01;  C[4] = 2.0f * k * a02;  C[5] = 2.0f * k * a12;
    C[6] = -2.0f * k * amx; C[7] = -2.0f * k * amy; C[8] = -2.0f * k * amz;
    C[9] = k * muAmu + log2f(opacities[g]);

    _Float16* rec = crec + (size_t)g * 32;
#pragma unroll
    for (int kk = 0; kk < 10; ++kk) {
        _Float16 h = (_Float16)C[kk];
        rec[kk]      = h;                              // Ch at K 0..9
        rec[10 + kk] = (_Float16)(C[kk] - (float)h);   // Cl at K 10..19
        rec[20 + kk] = h;                              // Ch again at K 20..29
    }
    rec[30] = (_Float16)0; rec[31] = (_Float16)0;

    const int cidx = g >> 5, r = g & 31;
    const int gt = r >> 4, grpW = (r >> 2) & 3, i = r & 3;
    const int p = grpW * 8 + gt * 4 + i;
#pragma unroll
    for (int c = 0; c < N_CLASSES; ++c)
        semP[(size_t)c * N_GAUSS + cidx * 32 + p] = (_Float16)semantics[g * N_CLASSES + c];
}

// ---------------------------------------------------------------------------
// Main: 256 blocks (1/CU) x 512 threads (8 waves). Each block owns one
// 64-point group and ALL 100 chunks; wave wid owns chunks wid*12.5 (12-13).
// NO split dimension: no atomics, no output pre-zeroing, plain coalesced
// stores. The 12-deep loop software-pipelines the per-chunk VMEM (A0/A1/bS
// prefetched one chunk ahead, ~300cyc of MFMA+VALU+LDS covers L2 latency) --
// this replaces R11's 3-iteration loop whose loads couldn't pipeline.
// Per chunk (64 pts x 32 g):
//   Q-phase: 8 MFMAs ([Ch|Cl|Ch]x[Ph|Ph|Pl] one-shot 3-term contraction),
//   exp2 on D-frags, cvt_pk, one swizzled b128 LDS write per s-tile,
//   PV-phase: 4 A-frag reads + 4 MFMAs vs semP.
// Epilogue: LDS 8-way reduce + plain coalesced stores.
// ---------------------------------------------------------------------------
__launch_bounds__(512, 2)
__global__ void gauss_occ_main_kernel(const float* __restrict__ xyz,
                                      const _Float16* __restrict__ crec,
                                      const _Float16* __restrict__ semP,
                                      float* __restrict__ out) {
    __shared__ unsigned int wbuf[8][64][16];   // 32 KiB: per-wave 4 KiB tile

    const int tid  = threadIdx.x;
    const int lane = tid & 63;
    const int wid  = __builtin_amdgcn_readfirstlane(tid >> 6);
    const int pg   = blockIdx.x;                     // 0..255 point-group
    const int c0 = (wid * NCHUNK) >> 3;              // wid*12.5
    const int c1 = ((wid + 1) * NCHUNK) >> 3;

    const int m   = lane & 15;
    const int mm  = (m < N_CLASSES) ? m : (N_CLASSES - 1);
    const int grp = lane >> 4;
    const int frs = (m >> 1) & 3;          // swizzle key for rows s*16+m
    const int wsz = (lane >> 1) & 3;       // swizzle key for row lane

    const int pt = pg * 64 + lane;
    const float x = xyz[pt * 3 + 0];
    const float y = xyz[pt * 3 + 1];
    const float z = xyz[pt * 3 + 2];

    unsigned int (*wrow)[16] = wbuf[wid];

    // ---- one-time: stage expanded 32-slot B-row [Ph|Ph|Pl|00] per point ----
    {
        float P[10] = {x * x, y * y, z * z, x * y, x * z, y * z, x, y, z, 1.0f};
        _Float16 Ph[10], Pl[10];
#pragma unroll
        for (int j = 0; j < 10; ++j) {
            Ph[j] = (_Float16)P[j];
            Pl[j] = (_Float16)(P[j] - (float)Ph[j]);   // exact residual
        }
        half8 b0, b1, b2, b3;
#pragma unroll
        for (int j = 0; j < 8; ++j) b0[j] = Ph[j];                 // K0-7
        b1[0] = Ph[8]; b1[1] = Ph[9];
#pragma unroll
        for (int j = 0; j < 6; ++j) b1[2 + j] = Ph[j];             // K8-15
#pragma unroll
        for (int j = 0; j < 4; ++j) { b2[j] = Ph[6 + j]; b2[4 + j] = Pl[j]; }  // K16-23
#pragma unroll
        for (int j = 0; j < 6; ++j) b3[j] = Pl[4 + j];             // K24-29
        b3[6] = (_Float16)0; b3[7] = (_Float16)0;                  // K30-31
        *(half8*)&wrow[lane][(0 ^ wsz) * 4] = b0;
        *(half8*)&wrow[lane][(1 ^ wsz) * 4] = b1;
        *(half8*)&wrow[lane][(2 ^ wsz) * 4] = b2;
        *(half8*)&wrow[lane][(3 ^ wsz) * 4] = b3;
    }

    // gather Q B-fragments: lane (m,grp) needs block grp of point s*16+m
    half8 f1[4];
#pragma unroll
    for (int s = 0; s < 4; ++s)
        f1[s] = *(const half8*)&wrow[s * 16 + m][(grp ^ frs) * 4];

    f32x4 acc0 = {0.f, 0.f, 0.f, 0.f};
    f32x4 acc1 = {0.f, 0.f, 0.f, 0.f};
    f32x4 acc2 = {0.f, 0.f, 0.f, 0.f};
    f32x4 acc3 = {0.f, 0.f, 0.f, 0.f};
    const f32x4 z4 = {0.f, 0.f, 0.f, 0.f};

    // ---- software-pipelined main loop: prefetch chunk c+1 during c ----
    size_t rb = ((size_t)(c0 * 32 + m)) * 32 + (size_t)grp * 8;
    half8 A0 = *(const half8*)(crec + rb);
    half8 A1 = *(const half8*)(crec + rb + 16 * 32);
    half8 bS = *(const half8*)(semP + (size_t)mm * N_GAUSS + c0 * 32 + grp * 8);

    for (int c = c0; c < c1; ++c) {
        const int cn = (c + 1 < c1) ? (c + 1) : c;   // uniform; last iter re-loads
        const size_t rbn = ((size_t)(cn * 32 + m)) * 32 + (size_t)grp * 8;
        const half8 nA0 = *(const half8*)(crec + rbn);
        const half8 nA1 = *(const half8*)(crec + rbn + 16 * 32);
        const half8 nbS = *(const half8*)(semP + (size_t)mm * N_GAUSS + cn * 32 + grp * 8);

        // ---- Q-MFMAs + exp + pack + staged write, per point-subtile s ----
#pragma unroll
        for (int s = 0; s < 4; ++s) {
            f32x4 t0 = __builtin_amdgcn_mfma_f32_16x16x32_f16(A0, f1[s], z4, 0, 0, 0);
            f32x4 t1 = __builtin_amdgcn_mfma_f32_16x16x32_f16(A1, f1[s], z4, 0, 0, 0);

            half2v h01, h23, h45, h67;
            h01[0] = (_Float16)__builtin_amdgcn_exp2f(t0[0]);
            h01[1] = (_Float16)__builtin_amdgcn_exp2f(t0[1]);
            h23[0] = (_Float16)__builtin_amdgcn_exp2f(t0[2]);
            h23[1] = (_Float16)__builtin_amdgcn_exp2f(t0[3]);
            h45[0] = (_Float16)__builtin_amdgcn_exp2f(t1[0]);
            h45[1] = (_Float16)__builtin_amdgcn_exp2f(t1[1]);
            h67[0] = (_Float16)__builtin_amdgcn_exp2f(t1[2]);
            h67[1] = (_Float16)__builtin_amdgcn_exp2f(t1[3]);

            *(uint4*)&wrow[s * 16 + m][(grp ^ frs) * 4] =
                make_uint4(__builtin_bit_cast(unsigned int, h01),
                           __builtin_bit_cast(unsigned int, h23),
                           __builtin_bit_cast(unsigned int, h45),
                           __builtin_bit_cast(unsigned int, h67));
        }

        // ---- PV-phase: A-frag reads + 4 MFMAs ----
        const half8 a0 = *(const half8*)&wrow[ 0 + m][(grp ^ frs) * 4];
        const half8 a1 = *(const half8*)&wrow[16 + m][(grp ^ frs) * 4];
        const half8 a2 = *(const half8*)&wrow[32 + m][(grp ^ frs) * 4];
        const half8 a3 = *(const half8*)&wrow[48 + m][(grp ^ frs) * 4];
        acc0 = __builtin_amdgcn_mfma_f32_16x16x32_f16(a0, bS, acc0, 0, 0, 0);
        acc1 = __builtin_amdgcn_mfma_f32_16x16x32_f16(a1, bS, acc1, 0, 0, 0);
        acc2 = __builtin_amdgcn_mfma_f32_16x16x32_f16(a2, bS, acc2, 0, 0, 0);
        acc3 = __builtin_amdgcn_mfma_f32_16x16x32_f16(a3, bS, acc3, 0, 0, 0);

        A0 = nA0; A1 = nA1; bS = nbS;
    }

    // ---- epilogue: dump acc into own LDS region, 8-way reduce, store ----
    float* red = (float*)&wbuf[0][0][0];
#pragma unroll
    for (int i = 0; i < 4; ++i) {
        red[wid * 1024 + ( 0 + grp * 4 + i) * 16 + m] = acc0[i];
        red[wid * 1024 + (16 + grp * 4 + i) * 16 + m] = acc1[i];
        red[wid * 1024 + (32 + grp * 4 + i) * 16 + m] = acc2[i];
        red[wid * 1024 + (48 + grp * 4 + i) * 16 + m] = acc3[i];
    }
    __syncthreads();

    // 896 outputs per block; idx = l*14+cc -> address pg*896+idx: coalesced
    for (int idx = tid; idx < 64 * N_CLASSES; idx += 512) {
        const int l = idx / N_CLASSES;
        const int cc = idx - l * N_CLASSES;
        float s = 0.0f;
#pragma unroll
        for (int wq = 0; wq < 8; ++wq) s += red[wq * 1024 + l * 16 + cc];
        out[(size_t)pg * (64 * N_CLASSES) + idx] = s;
    }
}

extern "C" void kernel_launch(void* const* d_in, const int* in_sizes, int n_in,
                              void* d_out, int out_size, void* d_ws, size_t ws_size,
                              hipStream_t stream) {
    const float* xyz       = (const float*)d_in[0];
    const float* means     = (const float*)d_in[1];
    const float* scales    = (const float*)d_in[2];
    const float* rotations = (const float*)d_in[3];
    const float* opacities = (const float*)d_in[4];
    const float* semantics = (const float*)d_in[5];
    float* out = (float*)d_out;

    _Float16* crec = (_Float16*)((char*)d_ws + WS_CREC_OFF);
    _Float16* semP = (_Float16*)((char*)d_ws + WS_SEMP_OFF);

    hipLaunchKernelGGL(gauss_prep_kernel,
                       dim3(13), dim3(256), 0, stream,
                       means, scales, rotations, opacities, semantics, crec, semP);

    hipLaunchKernelGGL(gauss_occ_main_kernel,
                       dim3(256), dim3(512), 0, stream,
                       xyz, crec, semP, out);
}